// Round 3
// baseline (537.258 us; speedup 1.0000x reference)
//
#include <hip/hip_runtime.h>

typedef unsigned int u32;
typedef unsigned short u16;
typedef __attribute__((ext_vector_type(4))) float f32x4;
typedef __attribute__((ext_vector_type(4))) int i32x4;
typedef __attribute__((ext_vector_type(2))) int i32x2;
typedef __attribute__((ext_vector_type(8))) short s16x8;

#define N_NODES 8192
#define F_DIM 512

// Raw barrier WITHOUT vmcnt(0) drain — lets global_load_lds / prefetch loads
// stay in flight across the workgroup barrier.
#define BARRIER_NOVM() asm volatile("s_waitcnt lgkmcnt(0)\ns_barrier" ::: "memory")
#define WAITVM(n) asm volatile("s_waitcnt vmcnt(" #n ")" ::: "memory")

// XOR slot swizzle for the [m][k]-contiguous LDS tiles (row stride 128B, 8 slots of 16B).
__device__ __forceinline__ int fm_swz(int m) {
    return ((m >> 2) & 7) ^ ((m & 3) << 1);
}

__device__ __forceinline__ u16 f2bf(float x) {
    u32 u = __builtin_bit_cast(u32, x);
    u = (u + 0x7FFFu + ((u >> 16) & 1u)) >> 16;
    return (u16)u;
}

__device__ __forceinline__ void glds16(const u16* g, u16* l) {
    __builtin_amdgcn_global_load_lds((const __attribute__((address_space(1))) u32*)g,
                                     (__attribute__((address_space(3))) u32*)l, 16, 0, 0);
}

// ---------------- Kernel 1: Yt[f][i] = bf16( sum_c W[c][f] * X[i][c] ) ----------------
__global__ __launch_bounds__(256, 1)
void k1_xw(const float* __restrict__ X, const float* __restrict__ W, u16* __restrict__ Yt) {
    __shared__ __align__(16) u16 Wl[128 * 64];
    __shared__ __align__(16) u16 Xl[128 * 64];

    const int tid = threadIdx.x;
    const int lane = tid & 63;
    const int wave = tid >> 6;
    const int wm = wave >> 1, wn = wave & 1;
    const int col = lane & 15, quad = lane >> 4;

    const int f0 = (blockIdx.x & 3) * 128;   // M dim (f)
    const int i0 = (blockIdx.x >> 2) * 128;  // N dim (i)

    const int cgrp = tid & 31;  // W: f-group of 4
    const int kk   = tid >> 5;  // W: k-octet
    const int xcq  = tid & 15;  // X: c-quad group
    const int xig  = tid >> 4;  // X: i-group of 8

    f32x4 wr[8], xr[8];
    {
        const float* wp = W + (size_t)(kk * 8) * F_DIM + f0 + cgrp * 4;
        const float* xp = X + (size_t)(i0 + xig * 8) * F_DIM + xcq * 4;
#pragma unroll
        for (int r = 0; r < 8; ++r) wr[r] = *(const f32x4*)(wp + (size_t)r * F_DIM);
#pragma unroll
        for (int r = 0; r < 8; ++r) xr[r] = *(const f32x4*)(xp + (size_t)r * F_DIM);
    }

    f32x4 acc[4][4] = {};

    for (int s = 0; s < 8; ++s) {
        BARRIER_NOVM();
#pragma unroll
        for (int mm = 0; mm < 4; ++mm) {
            int m = cgrp * 4 + mm;
            u32 q0 = ((u32)f2bf(wr[1][mm]) << 16) | f2bf(wr[0][mm]);
            u32 q1 = ((u32)f2bf(wr[3][mm]) << 16) | f2bf(wr[2][mm]);
            u32 q2 = ((u32)f2bf(wr[5][mm]) << 16) | f2bf(wr[4][mm]);
            u32 q3 = ((u32)f2bf(wr[7][mm]) << 16) | f2bf(wr[6][mm]);
            i32x4 v = {(int)q0, (int)q1, (int)q2, (int)q3};
            *(i32x4*)&Wl[m * 64 + ((kk ^ fm_swz(m)) << 3)] = v;
        }
#pragma unroll
        for (int r = 0; r < 8; ++r) {
            int row = xig * 8 + r;
            u32 a = ((u32)f2bf(xr[r][1]) << 16) | f2bf(xr[r][0]);
            u32 b = ((u32)f2bf(xr[r][3]) << 16) | f2bf(xr[r][2]);
            int kc = xcq >> 1, half = xcq & 1;
            i32x2 v = {(int)a, (int)b};
            *(i32x2*)&Xl[row * 64 + ((kc ^ (row & 7)) << 3) + half * 4] = v;
        }
        BARRIER_NOVM();
        if (s + 1 < 8) {
            int c0 = (s + 1) * 64;
            const float* wp = W + (size_t)(c0 + kk * 8) * F_DIM + f0 + cgrp * 4;
            const float* xp = X + (size_t)(i0 + xig * 8) * F_DIM + c0 + xcq * 4;
#pragma unroll
            for (int r = 0; r < 8; ++r) wr[r] = *(const f32x4*)(wp + (size_t)r * F_DIM);
#pragma unroll
            for (int r = 0; r < 8; ++r) xr[r] = *(const f32x4*)(xp + (size_t)r * F_DIM);
        }
#pragma unroll
        for (int s2 = 0; s2 < 2; ++s2) {
            s16x8 af[4], bfr[4];
#pragma unroll
            for (int mi = 0; mi < 4; ++mi) {
                int m = wm * 64 + mi * 16 + col;
                int kc = s2 * 4 + quad;
                af[mi] = *(const s16x8*)&Wl[m * 64 + ((kc ^ fm_swz(m)) << 3)];
            }
#pragma unroll
            for (int ni = 0; ni < 4; ++ni) {
                int rr = wn * 64 + ni * 16 + col;
                int kc = s2 * 4 + quad;
                bfr[ni] = *(const s16x8*)&Xl[rr * 64 + ((kc ^ (rr & 7)) << 3)];
            }
#pragma unroll
            for (int mi = 0; mi < 4; ++mi)
#pragma unroll
                for (int ni = 0; ni < 4; ++ni)
                    acc[mi][ni] = __builtin_amdgcn_mfma_f32_16x16x32_bf16(af[mi], bfr[ni],
                                                                          acc[mi][ni], 0, 0, 0);
        }
    }

#pragma unroll
    for (int mi = 0; mi < 4; ++mi)
#pragma unroll
        for (int r = 0; r < 4; ++r) {
            int f = f0 + wm * 64 + mi * 16 + quad * 4 + r;
#pragma unroll
            for (int ni = 0; ni < 4; ++ni) {
                int i = i0 + wn * 64 + ni * 16 + col;
                Yt[(size_t)f * N_NODES + i] = f2bf(acc[mi][ni][r]);
            }
        }
}

// -------- Kernel 2: out[j][f] = relu( rsqrt(max(deg_j,1)) * sum_i adj[i][j]*Y[i][f] ) --------
// j-tile 64 (grid 512) + 64 KB LDS -> 2 blocks/CU, 2 waves/SIMD: cross-block latency hiding.
__global__ __launch_bounds__(256, 2)
void k2_agg(const int* __restrict__ adj, const u16* __restrict__ Yt, float* __restrict__ out) {
    __shared__ __align__(16) u16 Ab[2][64 * 64];   // A double buffer (8 KB each)
    __shared__ __align__(16) u16 Bb[3][128 * 64];  // B triple buffer (16 KB each)
    // total LDS = 64 KB -> 2 blocks/CU; degs overlays Ab after the K-loop

    const int tid = threadIdx.x;
    const int lane = tid & 63;
    const int wave = tid >> 6;
    const int wm = wave >> 1, wn = wave & 1;  // 2x2 waves over 64j x 128f
    const int col = lane & 15, quad = lane >> 4;

    // 4 f-tiles of the same j-stripe share blockIdx%8 -> same XCD L2 (128 ≡ 0 mod 8)
    const int j0 = (blockIdx.x & 127) * 64;
    const int f0 = (blockIdx.x >> 7) * 128;

    const int cgrp = tid & 15;  // j-group of 4 (16 groups x 4 = 64 j)
    const int kk = tid >> 4;    // i-quartet (16 x 4 = 64 i-rows)

    u32 dacc[4] = {0, 0, 0, 0};
    i32x4 avA[4], avB[4];

    const int rowl = lane >> 3;
    const int kcB = (lane & 7) ^ rowl;  // XOR-swizzled chunk this lane fetches

    auto loadA = [&](int i0k, i32x4 (&av)[4]) {
        const int* ap = adj + (size_t)(i0k + kk * 4) * N_NODES + j0 + cgrp * 4;
#pragma unroll
        for (int r = 0; r < 4; ++r) av[r] = *(const i32x4*)(ap + (size_t)r * N_NODES);
    };
    auto stageB = [&](int i0k, int buf) {
#pragma unroll
        for (int gg = 0; gg < 4; ++gg) {
            int g = wave * 4 + gg;
            const u16* src = Yt + (size_t)(f0 + g * 8 + rowl) * N_NODES + i0k + kcB * 8;
            glds16(src, &Bb[buf][g * 512]);
        }
    };
    auto writeA = [&](const i32x4 (&av)[4], int buf) {
#pragma unroll
        for (int mm = 0; mm < 4; ++mm) {
            int m = cgrp * 4 + mm;
            u32 p0 = (u32)av[0][mm] | ((u32)av[1][mm] << 16);
            u32 p1 = (u32)av[2][mm] | ((u32)av[3][mm] << 16);
            dacc[mm] += p0 + p1;  // halves accumulate <=256 over 128 steps — no carry
            int slot = kk >> 1, half = kk & 1;
            i32x2 v = {(int)(p0 * 0x3F80u), (int)(p1 * 0x3F80u)};
            *(i32x2*)&Ab[buf][m * 64 + (((slot ^ fm_swz(m)) << 3)) + half * 4] = v;
        }
    };

    f32x4 acc[2][4] = {};

    // prologue: stage steps 0 and 1 (2-deep pipeline); 8 vm ops per step
    loadA(0, avA);
    stageB(0, 0);
    loadA(64, avB);
    stageB(64, 1);
    writeA(avA, 0);
    WAITVM(8);  // drain step-0's glds (8 newest = step-1's ops)
    BARRIER_NOVM();

    for (int s = 0; s < 128; ++s) {
        if (s + 2 < 128) {
            if (s & 1) loadA((s + 2) * 64, avB);
            else       loadA((s + 2) * 64, avA);
            stageB((s + 2) * 64, (s + 2) % 3);
        }
        // MFMA on tile s
        const u16* A = Ab[s & 1];
        const u16* B = Bb[s % 3];
#pragma unroll
        for (int s2 = 0; s2 < 2; ++s2) {
            s16x8 af[2], bfr[4];
#pragma unroll
            for (int mi = 0; mi < 2; ++mi) {
                int m = wm * 32 + mi * 16 + col;
                int kc = s2 * 4 + quad;
                af[mi] = *(const s16x8*)&A[m * 64 + ((kc ^ fm_swz(m)) << 3)];
            }
#pragma unroll
            for (int ni = 0; ni < 4; ++ni) {
                int rr = wn * 64 + ni * 16 + col;
                int kc = s2 * 4 + quad;
                bfr[ni] = *(const s16x8*)&B[rr * 64 + ((kc ^ (rr & 7)) << 3)];
            }
#pragma unroll
            for (int mi = 0; mi < 2; ++mi)
#pragma unroll
                for (int ni = 0; ni < 4; ++ni)
                    acc[mi][ni] = __builtin_amdgcn_mfma_f32_16x16x32_bf16(af[mi], bfr[ni],
                                                                          acc[mi][ni], 0, 0, 0);
        }
        if (s + 1 < 128) {
            if (s & 1) writeA(avA, (s + 1) & 1);  // data(s+1) loaded 2 steps ago
            else       writeA(avB, (s + 1) & 1);
        }
        if (s + 2 < 128) { WAITVM(8); }  // keep this step's 8 issues in flight
        else             { WAITVM(0); }  // tail: no new issues to push the count — full drain
        BARRIER_NOVM();
    }

    // degree reduction — overlay on Ab (K-loop done with it)
    int* degs = (int*)&Ab[0][0];
    if (tid < 64) degs[tid] = 0;
    __syncthreads();
#pragma unroll
    for (int mm = 0; mm < 4; ++mm) {
        int d = (int)((dacc[mm] & 0xFFFFu) + (dacc[mm] >> 16));
        atomicAdd(&degs[cgrp * 4 + mm], d);
    }
    __syncthreads();

    // fused norm + relu epilogue
#pragma unroll
    for (int mi = 0; mi < 2; ++mi)
#pragma unroll
        for (int r = 0; r < 4; ++r) {
            int jl = wm * 32 + mi * 16 + quad * 4 + r;
            float nv = rsqrtf(fmaxf((float)degs[jl], 1.0f));
            size_t ob = (size_t)(j0 + jl) * F_DIM + f0 + wn * 64;
#pragma unroll
            for (int ni = 0; ni < 4; ++ni) {
                float v = acc[mi][ni][r] * nv;
                out[ob + ni * 16 + col] = fmaxf(v, 0.0f);
            }
        }
}

extern "C" void kernel_launch(void* const* d_in, const int* in_sizes, int n_in,
                              void* d_out, int out_size, void* d_ws, size_t ws_size,
                              hipStream_t stream) {
    (void)in_sizes; (void)n_in; (void)out_size; (void)ws_size;
    const float* X = (const float*)d_in[0];
    const int* adj = (const int*)d_in[1];
    const float* W = (const float*)d_in[2];
    float* out = (float*)d_out;
    u16* Yt = (u16*)d_ws;  // 512*8192 bf16 = 8 MiB

    k1_xw<<<dim3(256), dim3(256), 0, stream>>>(X, W, Yt);
    k2_agg<<<dim3(512), dim3(256), 0, stream>>>(adj, Yt, out);
}

// Round 4
// 494.363 us; speedup vs baseline: 1.0868x; 1.0868x over previous
//
#include <hip/hip_runtime.h>

typedef unsigned int u32;
typedef unsigned short u16;
typedef __attribute__((ext_vector_type(4))) float f32x4;
typedef __attribute__((ext_vector_type(4))) int i32x4;
typedef __attribute__((ext_vector_type(2))) int i32x2;
typedef __attribute__((ext_vector_type(8))) short s16x8;

#define N_NODES 8192
#define F_DIM 512

// Raw barrier WITHOUT vmcnt(0) drain — keep prefetch loads in flight across it.
#define BARRIER_NOVM() asm volatile("s_waitcnt lgkmcnt(0)\ns_barrier" ::: "memory")
#define WAITVM(n) asm volatile("s_waitcnt vmcnt(" #n ")" ::: "memory")

// XOR slot swizzle for [m][k]-contiguous LDS tiles (row stride 128B, 8 slots of 16B).
__device__ __forceinline__ int fm_swz(int m) {
    return ((m >> 2) & 7) ^ ((m & 3) << 1);
}

__device__ __forceinline__ u16 f2bf(float x) {
    u32 u = __builtin_bit_cast(u32, x);
    u = (u + 0x7FFFu + ((u >> 16) & 1u)) >> 16;
    return (u16)u;
}

__device__ __forceinline__ void glds16(const u16* g, u16* l) {
    __builtin_amdgcn_global_load_lds((const __attribute__((address_space(1))) u32*)g,
                                     (__attribute__((address_space(3))) u32*)l, 16, 0, 0);
}

// A,B: [128 rows][64 k] bf16, row stride 64 elems; A slots swizzled fm_swz(row), B by (row&7).
__device__ __forceinline__ void mfma_step(const u16* A, const u16* B, int wm, int wn,
                                          int col, int quad, f32x4 (&acc)[4][4]) {
#pragma unroll
    for (int s2 = 0; s2 < 2; ++s2) {
        s16x8 af[4], bfr[4];
#pragma unroll
        for (int mi = 0; mi < 4; ++mi) {
            int m = wm * 64 + mi * 16 + col;
            int kc = s2 * 4 + quad;
            af[mi] = *(const s16x8*)&A[m * 64 + ((kc ^ fm_swz(m)) << 3)];
        }
#pragma unroll
        for (int ni = 0; ni < 4; ++ni) {
            int rr = wn * 64 + ni * 16 + col;
            int kc = s2 * 4 + quad;
            bfr[ni] = *(const s16x8*)&B[rr * 64 + ((kc ^ (rr & 7)) << 3)];
        }
#pragma unroll
        for (int mi = 0; mi < 4; ++mi)
#pragma unroll
            for (int ni = 0; ni < 4; ++ni)
                acc[mi][ni] = __builtin_amdgcn_mfma_f32_16x16x32_bf16(af[mi], bfr[ni],
                                                                      acc[mi][ni], 0, 0, 0);
    }
}

// ---------------- Kernel 1: Yt[f][i] = bf16( sum_c W[c][f] * X[i][c] ) ----------------
__global__ __launch_bounds__(256, 1)
void k1_xw(const float* __restrict__ X, const float* __restrict__ W, u16* __restrict__ Yt) {
    __shared__ __align__(16) u16 Wl[128 * 64];
    __shared__ __align__(16) u16 Xl[128 * 64];

    const int tid = threadIdx.x;
    const int lane = tid & 63;
    const int wave = tid >> 6;
    const int wm = wave >> 1, wn = wave & 1;
    const int col = lane & 15, quad = lane >> 4;

    const int f0 = (blockIdx.x & 3) * 128;   // M dim (f)
    const int i0 = (blockIdx.x >> 2) * 128;  // N dim (i)

    const int cgrp = tid & 31;
    const int kk   = tid >> 5;
    const int xcq  = tid & 15;
    const int xig  = tid >> 4;

    f32x4 wr[8], xr[8];
    {
        const float* wp = W + (size_t)(kk * 8) * F_DIM + f0 + cgrp * 4;
        const float* xp = X + (size_t)(i0 + xig * 8) * F_DIM + xcq * 4;
#pragma unroll
        for (int r = 0; r < 8; ++r) wr[r] = *(const f32x4*)(wp + (size_t)r * F_DIM);
#pragma unroll
        for (int r = 0; r < 8; ++r) xr[r] = *(const f32x4*)(xp + (size_t)r * F_DIM);
    }

    f32x4 acc[4][4] = {};

    for (int s = 0; s < 8; ++s) {
        BARRIER_NOVM();
#pragma unroll
        for (int mm = 0; mm < 4; ++mm) {
            int m = cgrp * 4 + mm;
            u32 q0 = ((u32)f2bf(wr[1][mm]) << 16) | f2bf(wr[0][mm]);
            u32 q1 = ((u32)f2bf(wr[3][mm]) << 16) | f2bf(wr[2][mm]);
            u32 q2 = ((u32)f2bf(wr[5][mm]) << 16) | f2bf(wr[4][mm]);
            u32 q3 = ((u32)f2bf(wr[7][mm]) << 16) | f2bf(wr[6][mm]);
            i32x4 v = {(int)q0, (int)q1, (int)q2, (int)q3};
            *(i32x4*)&Wl[m * 64 + ((kk ^ fm_swz(m)) << 3)] = v;
        }
#pragma unroll
        for (int r = 0; r < 8; ++r) {
            int row = xig * 8 + r;
            u32 a = ((u32)f2bf(xr[r][1]) << 16) | f2bf(xr[r][0]);
            u32 b = ((u32)f2bf(xr[r][3]) << 16) | f2bf(xr[r][2]);
            int kc = xcq >> 1, half = xcq & 1;
            i32x2 v = {(int)a, (int)b};
            *(i32x2*)&Xl[row * 64 + ((kc ^ (row & 7)) << 3) + half * 4] = v;
        }
        BARRIER_NOVM();
        if (s + 1 < 8) {
            int c0 = (s + 1) * 64;
            const float* wp = W + (size_t)(c0 + kk * 8) * F_DIM + f0 + cgrp * 4;
            const float* xp = X + (size_t)(i0 + xig * 8) * F_DIM + c0 + xcq * 4;
#pragma unroll
            for (int r = 0; r < 8; ++r) wr[r] = *(const f32x4*)(wp + (size_t)r * F_DIM);
#pragma unroll
            for (int r = 0; r < 8; ++r) xr[r] = *(const f32x4*)(xp + (size_t)r * F_DIM);
        }
        mfma_step(Wl, Xl, wm, wn, col, quad, acc);
    }

#pragma unroll
    for (int mi = 0; mi < 4; ++mi)
#pragma unroll
        for (int r = 0; r < 4; ++r) {
            int f = f0 + wm * 64 + mi * 16 + quad * 4 + r;
#pragma unroll
            for (int ni = 0; ni < 4; ++ni) {
                int i = i0 + wn * 64 + ni * 16 + col;
                Yt[(size_t)f * N_NODES + i] = f2bf(acc[mi][ni][r]);
            }
        }
}

// -------- Kernel 2: partial[j][f] = sum_{i in half} adj[i][j]*Y[i][f]; partial degrees --------
// 128x128 tile, K-split 2 -> grid 512, 2 blocks/CU (2x80KB LDS = full pool), vmcnt pipeline.
__global__ __launch_bounds__(256, 2)
void k2_agg(const int* __restrict__ adj, const u16* __restrict__ Yt,
            float* __restrict__ p0, float* __restrict__ p1, int* __restrict__ degp) {
    __shared__ __align__(16) u16 Ab[2][128 * 64];  // 2 x 16 KB
    __shared__ __align__(16) u16 Bb[3][128 * 64];  // 3 x 16 KB  (total 80 KB)

    const int tid = threadIdx.x;
    const int lane = tid & 63;
    const int wave = tid >> 6;
    const int wm = wave >> 1, wn = wave & 1;
    const int col = lane & 15, quad = lane >> 4;

    // bid = f_idx*128 + khalf*64 + stripe : the 4 f-tiles of a (stripe,khalf) share bid%8 (XCD/L2)
    const int f_idx = blockIdx.x >> 7;
    const int unit = blockIdx.x & 127;
    const int khalf = unit >> 6;
    const int stripe = unit & 63;
    const int j0 = stripe * 128;
    const int f0 = f_idx * 128;
    const int ibase = khalf * 4096;
    float* __restrict__ part = khalf ? p1 : p0;

    const int cgrp = tid & 31;  // j-group of 4 (32 x 4 = 128 j)
    const int kk = tid >> 5;    // i-octet (8 x 8 = 64 i)

    u32 dacc[4] = {0, 0, 0, 0};
    i32x4 avA[8], avB[8];

    const int rowl = lane >> 3;
    const int kcB = (lane & 7) ^ rowl;

    auto loadA = [&](int i0k, i32x4 (&av)[8]) {
        const int* ap = adj + (size_t)(i0k + kk * 8) * N_NODES + j0 + cgrp * 4;
#pragma unroll
        for (int r = 0; r < 8; ++r) av[r] = *(const i32x4*)(ap + (size_t)r * N_NODES);
    };
    auto stageB = [&](int i0k, int buf) {
#pragma unroll
        for (int gg = 0; gg < 4; ++gg) {
            int g = wave * 4 + gg;
            const u16* src = Yt + (size_t)(f0 + g * 8 + rowl) * N_NODES + i0k + kcB * 8;
            glds16(src, &Bb[buf][g * 512]);
        }
    };
    auto writeA = [&](const i32x4 (&av)[8], int buf) {
#pragma unroll
        for (int mm = 0; mm < 4; ++mm) {
            int m = cgrp * 4 + mm;
            u32 q0 = (u32)av[0][mm] | ((u32)av[1][mm] << 16);
            u32 q1 = (u32)av[2][mm] | ((u32)av[3][mm] << 16);
            u32 q2 = (u32)av[4][mm] | ((u32)av[5][mm] << 16);
            u32 q3 = (u32)av[6][mm] | ((u32)av[7][mm] << 16);
            dacc[mm] += q0 + q1 + q2 + q3;  // halves bounded by 4096 — no carry
            i32x4 v = {(int)(q0 * 0x3F80u), (int)(q1 * 0x3F80u),
                       (int)(q2 * 0x3F80u), (int)(q3 * 0x3F80u)};
            *(i32x4*)&Ab[buf][m * 64 + ((kk ^ fm_swz(m)) << 3)] = v;
        }
    };

    f32x4 acc[4][4] = {};

    // prologue: 2-deep pipeline; 12 vm ops per step (8 adj + 4 glds)
    loadA(ibase, avA);
    stageB(ibase, 0);
    loadA(ibase + 64, avB);
    stageB(ibase + 64, 1);
    writeA(avA, 0);
    WAITVM(12);  // tile-0 glds complete (12 newest = tile-1's ops)
    BARRIER_NOVM();

    for (int s = 0; s < 64; ++s) {
        if (s + 2 < 64) {
            if (s & 1) loadA(ibase + (s + 2) * 64, avB);
            else       loadA(ibase + (s + 2) * 64, avA);
            stageB(ibase + (s + 2) * 64, (s + 2) % 3);
        }
        mfma_step(Ab[s & 1], Bb[s % 3], wm, wn, col, quad, acc);
        if (s + 1 < 64) {
            if (s & 1) writeA(avA, (s + 1) & 1);
            else       writeA(avB, (s + 1) & 1);
        }
        if (s + 2 < 64) { WAITVM(12); }
        else            { WAITVM(0); }  // tail: nothing new issued — full drain
        BARRIER_NOVM();
    }

    // per-half degree (only f_idx==0 blocks, no atomics in global)
    int* degs = (int*)&Ab[0][0];
    if (tid < 128) degs[tid] = 0;
    __syncthreads();
#pragma unroll
    for (int mm = 0; mm < 4; ++mm) {
        int d = (int)((dacc[mm] & 0xFFFFu) + (dacc[mm] >> 16));
        atomicAdd(&degs[cgrp * 4 + mm], d);
    }
    __syncthreads();
    if (f_idx == 0 && tid < 128) degp[khalf * N_NODES + j0 + tid] = degs[tid];

    // store raw fp32 partials (norm+relu deferred to k3)
#pragma unroll
    for (int mi = 0; mi < 4; ++mi)
#pragma unroll
        for (int r = 0; r < 4; ++r) {
            int jl = wm * 64 + mi * 16 + quad * 4 + r;
            size_t ob = (size_t)(j0 + jl) * F_DIM + f0 + wn * 64;
#pragma unroll
            for (int ni = 0; ni < 4; ++ni)
                part[ob + ni * 16 + col] = acc[mi][ni][r];
        }
}

// -------- Kernel 3: out = relu( rsqrt(max(deg,1)) * (p0+p1) ) --------
__global__ __launch_bounds__(256, 4)
void k3_combine(const float* __restrict__ p0, const float* __restrict__ p1,
                const int* __restrict__ degp, float* __restrict__ out) {
    int idx = blockIdx.x * 256 + threadIdx.x;  // one f32x4 per thread
    int j = idx >> 7;
    int c = (idx & 127) * 4;
    size_t off = (size_t)j * F_DIM + c;
    f32x4 a = *(const f32x4*)(p0 + off);
    f32x4 b = *(const f32x4*)(p1 + off);
    int d = degp[j] + degp[N_NODES + j];
    float nv = rsqrtf(fmaxf((float)d, 1.0f));
    f32x4 v;
#pragma unroll
    for (int t = 0; t < 4; ++t) v[t] = fmaxf((a[t] + b[t]) * nv, 0.0f);
    *(f32x4*)(out + off) = v;
}

extern "C" void kernel_launch(void* const* d_in, const int* in_sizes, int n_in,
                              void* d_out, int out_size, void* d_ws, size_t ws_size,
                              hipStream_t stream) {
    (void)in_sizes; (void)n_in; (void)out_size; (void)ws_size;
    const float* X = (const float*)d_in[0];
    const int* adj = (const int*)d_in[1];
    const float* W = (const float*)d_in[2];
    float* out = (float*)d_out;

    // ws layout: Yt 8 MB | p0 16 MB | p1 16 MB | degp 64 KB  (total ~40.1 MB)
    char* w = (char*)d_ws;
    u16* Yt = (u16*)w;
    float* p0 = (float*)(w + (8u << 20));
    float* p1 = p0 + (size_t)N_NODES * F_DIM;
    int* degp = (int*)(w + (8u << 20) + (size_t)2 * N_NODES * F_DIM * 4);

    k1_xw<<<dim3(256), dim3(256), 0, stream>>>(X, W, Yt);
    k2_agg<<<dim3(512), dim3(256), 0, stream>>>(adj, Yt, p0, p1, degp);
    k3_combine<<<dim3((N_NODES * F_DIM / 4) / 256), dim3(256), 0, stream>>>(p0, p1, degp, out);
}